// Round 2
// baseline (1342.024 us; speedup 1.0000x reference)
//
#include <hip/hip_runtime.h>
#include <hip/hip_bf16.h>

// CustomQuantLinear: out[m][n] = scale[n] * sum_k x[m][k]*(w[n][k]-zp[n]) + bias[n]
// M=8192 (B*S), N=11008 (OUT), K=4096 (IN)
// Strategy: (w-zp) is exactly representable in bf16 (|v|<=255, 8-bit significand),
// so pre-dequant W' to bf16 (lossless), round x to bf16, run bf16 MFMA GEMM
// (m97 structure: 128x128 tile, BK=32, 4 waves, global_load_lds width 16),
// apply scale/bias in fp32 epilogue.
// NOTE: harness upcasts the reference's fp16 `scale` to fp32 on push
// (supported input dtypes are {bf16, f32, int32}) -> read scale as float.

#define MDIM 8192
#define NDIM 11008
#define KDIM 4096

#define BM 128
#define BN 128
#define BK 32

typedef unsigned short u16;
typedef __bf16 bf16x8 __attribute__((ext_vector_type(8)));
typedef float f32x4 __attribute__((ext_vector_type(4)));
typedef u16 u16x8 __attribute__((ext_vector_type(8)));

// ---------- conversion kernels ----------

// exact: value is small integer (|v|<=255), fits bf16's 8-bit significand
__device__ __forceinline__ u16 f2bf_exact(float f) {
    return (u16)(__float_as_uint(f) >> 16);
}
// round-to-nearest-even
__device__ __forceinline__ u16 f2bf_rne(float f) {
    unsigned u = __float_as_uint(f);
    u += 0x7fffu + ((u >> 16) & 1u);
    return (u16)(u >> 16);
}

__global__ void conv_w(const int* __restrict__ w, const int* __restrict__ zp,
                       u16* __restrict__ wb) {
    const int idx = blockIdx.x * blockDim.x + threadIdx.x; // 8 elems each
    const int e = idx << 3;                                 // < 45,088,768
    const int row = e >> 12;                                // /KDIM
    const int z = zp[row];
    const int4 a = *(const int4*)(w + e);
    const int4 b = *(const int4*)(w + e + 4);
    u16x8 v;
    v[0] = f2bf_exact((float)(a.x - z));
    v[1] = f2bf_exact((float)(a.y - z));
    v[2] = f2bf_exact((float)(a.z - z));
    v[3] = f2bf_exact((float)(a.w - z));
    v[4] = f2bf_exact((float)(b.x - z));
    v[5] = f2bf_exact((float)(b.y - z));
    v[6] = f2bf_exact((float)(b.z - z));
    v[7] = f2bf_exact((float)(b.w - z));
    *(u16x8*)(wb + e) = v;
}

__global__ void conv_x(const float* __restrict__ x, u16* __restrict__ xb) {
    const int idx = blockIdx.x * blockDim.x + threadIdx.x;
    const int e = idx << 3;                                 // < 33,554,432
    const float4 a = *(const float4*)(x + e);
    const float4 b = *(const float4*)(x + e + 4);
    u16x8 v;
    v[0] = f2bf_rne(a.x);
    v[1] = f2bf_rne(a.y);
    v[2] = f2bf_rne(a.z);
    v[3] = f2bf_rne(a.w);
    v[4] = f2bf_rne(b.x);
    v[5] = f2bf_rne(b.y);
    v[6] = f2bf_rne(b.z);
    v[7] = f2bf_rne(b.w);
    *(u16x8*)(xb + e) = v;
}

// ---------- GEMM ----------

__device__ __forceinline__ void gload16(const u16* g, u16* l) {
    __builtin_amdgcn_global_load_lds(
        (const __attribute__((address_space(1))) unsigned int*)g,
        (__attribute__((address_space(3))) unsigned int*)l,
        16, 0, 0);
}

__global__ __launch_bounds__(256) void gemm_q(const u16* __restrict__ Xb,
                                              const u16* __restrict__ Wb,
                                              const float* __restrict__ scale,
                                              const float* __restrict__ bias,
                                              float* __restrict__ out) {
    __shared__ __align__(16) u16 As[BM * BK];
    __shared__ __align__(16) u16 Bs[BN * BK];

    const int t = threadIdx.x;
    const int w = t >> 6;
    const int lane = t & 63;
    const int bn0 = blockIdx.x * BN;
    const int bm0 = blockIdx.y * BM;

    // staging: thread t loads 8 bf16 (16B). row = t/4 (0..63), col = (t%4)*8
    const int sr = t >> 2;
    const int sc = (t & 3) << 3;
    const u16* gA = Xb + (bm0 + sr) * KDIM + sc;
    const u16* gB = Wb + (bn0 + sr) * KDIM + sc;
    // wave-uniform LDS dests (global_load_lds writes base + lane*16B)
    u16* lA0 = &As[(w * 16) * BK];
    u16* lA1 = &As[(64 + w * 16) * BK];
    u16* lB0 = &Bs[(w * 16) * BK];
    u16* lB1 = &Bs[(64 + w * 16) * BK];

    // wave 2x2 grid, each wave 64x64 output
    const int wm = w >> 1, wn = w & 1;
    const int lr = lane & 15;          // frag row/col
    const int lk = (lane >> 4) << 3;   // frag k-offset
    const u16* pA = &As[(wm * 64 + lr) * BK + lk];
    const u16* pB = &Bs[(wn * 64 + lr) * BK + lk];

    f32x4 acc[4][4];
#pragma unroll
    for (int i = 0; i < 4; ++i)
#pragma unroll
        for (int j = 0; j < 4; ++j) acc[i][j] = (f32x4){0.f, 0.f, 0.f, 0.f};

    for (int k0 = 0; k0 < KDIM; k0 += BK) {
        gload16(gA + k0, lA0);
        gload16(gA + 64 * KDIM + k0, lA1);
        gload16(gB + k0, lB0);
        gload16(gB + 64 * KDIM + k0, lB1);
        __syncthreads();   // drains vmcnt before barrier

        bf16x8 af[4], bfr[4];
#pragma unroll
        for (int i = 0; i < 4; ++i) af[i] = *(const bf16x8*)(pA + i * 16 * BK);
#pragma unroll
        for (int j = 0; j < 4; ++j) bfr[j] = *(const bf16x8*)(pB + j * 16 * BK);
#pragma unroll
        for (int i = 0; i < 4; ++i)
#pragma unroll
            for (int j = 0; j < 4; ++j)
                acc[i][j] = __builtin_amdgcn_mfma_f32_16x16x32_bf16(
                    af[i], bfr[j], acc[i][j], 0, 0, 0);
        __syncthreads();
    }

    // epilogue: C/D layout col = lane&15, row = (lane>>4)*4 + reg  [m89]
    const int rr = (lane >> 4) << 2;
#pragma unroll
    for (int j = 0; j < 4; ++j) {
        const int n = bn0 + wn * 64 + j * 16 + lr;
        const float s = scale[n];
        const float bi = bias[n];
#pragma unroll
        for (int i = 0; i < 4; ++i) {
            const int m = bm0 + wm * 64 + i * 16 + rr;
#pragma unroll
            for (int r = 0; r < 4; ++r) {
                out[(m + r) * NDIM + n] = acc[i][j][r] * s + bi;
            }
        }
    }
}

// ---------- fallback (ws too small) ----------

__global__ void naive_q(const float* __restrict__ x, const int* __restrict__ wq,
                        const float* __restrict__ scale, const int* __restrict__ zp,
                        const float* __restrict__ bias, float* __restrict__ out) {
    const long long idx = (long long)blockIdx.x * 256 + threadIdx.x;
    if (idx >= (long long)MDIM * NDIM) return;
    const int m = (int)(idx / NDIM);
    const int n = (int)(idx % NDIM);
    const float* xr = x + (long long)m * KDIM;
    const int* wr = wq + (long long)n * KDIM;
    float dot = 0.f, xs = 0.f;
    for (int k = 0; k < KDIM; ++k) {
        dot += xr[k] * (float)wr[k];
        xs += xr[k];
    }
    out[idx] = scale[n] * (dot - (float)zp[n] * xs) + bias[n];
}

extern "C" void kernel_launch(void* const* d_in, const int* in_sizes, int n_in,
                              void* d_out, int out_size, void* d_ws, size_t ws_size,
                              hipStream_t stream) {
    const float* x = (const float*)d_in[0];
    const int* wq = (const int*)d_in[1];
    const float* scale = (const float*)d_in[2];
    const int* zp = (const int*)d_in[3];
    const float* bias = (const float*)d_in[4];
    float* out = (float*)d_out;

    const size_t wb_bytes = (size_t)NDIM * KDIM * 2;  // 90,177,536
    const size_t xb_bytes = (size_t)MDIM * KDIM * 2;  // 67,108,864

    if (ws_size >= wb_bytes + xb_bytes) {
        u16* wb = (u16*)d_ws;
        u16* xb = (u16*)((char*)d_ws + wb_bytes);
        conv_w<<<NDIM * KDIM / 8 / 256, 256, 0, stream>>>(wq, zp, wb);
        conv_x<<<MDIM * KDIM / 8 / 256, 256, 0, stream>>>(x, xb);
        dim3 grid(NDIM / BN, MDIM / BM);  // (86, 64)
        gemm_q<<<grid, 256, 0, stream>>>(xb, wb, scale, bias, out);
    } else {
        const long long total = (long long)MDIM * NDIM;
        naive_q<<<(unsigned)((total + 255) / 256), 256, 0, stream>>>(
            x, wq, scale, zp, bias, out);
    }
}

// Round 3
// 997.222 us; speedup vs baseline: 1.3458x; 1.3458x over previous
//
#include <hip/hip_runtime.h>
#include <hip/hip_bf16.h>

// CustomQuantLinear: out[m][n] = scale[n] * sum_k x[m][k]*(w[n][k]-zp[n]) + bias[n]
// M=8192 (B*S), N=11008 (OUT), K=4096 (IN)
// R2 -> R3: measured 25x over-fetch (FETCH 3.85GB vs 157MB unique) from
// x-fastest dispatch re-streaming W' per grid-row. Fix: bijective XCD chunking
// + GROUP_M=8 grouped rasterization (pure index remap on the verified kernel).

#define MDIM 8192
#define NDIM 11008
#define KDIM 4096

#define BM 128
#define BN 128
#define BK 32
#define NTILE_N (NDIM / BN)   // 86
#define NTILE_M (MDIM / BM)   // 64
#define NWG (NTILE_N * NTILE_M) // 5504 (divisible by 8)
#define GROUP_M 8

typedef unsigned short u16;
typedef __bf16 bf16x8 __attribute__((ext_vector_type(8)));
typedef float f32x4 __attribute__((ext_vector_type(4)));
typedef u16 u16x8 __attribute__((ext_vector_type(8)));

// ---------- conversion kernels ----------

// exact: value is small integer (|v|<=255), fits bf16's 8-bit significand
__device__ __forceinline__ u16 f2bf_exact(float f) {
    return (u16)(__float_as_uint(f) >> 16);
}
// round-to-nearest-even
__device__ __forceinline__ u16 f2bf_rne(float f) {
    unsigned u = __float_as_uint(f);
    u += 0x7fffu + ((u >> 16) & 1u);
    return (u16)(u >> 16);
}

__global__ void conv_w(const int* __restrict__ w, const int* __restrict__ zp,
                       u16* __restrict__ wb) {
    const int idx = blockIdx.x * blockDim.x + threadIdx.x; // 8 elems each
    const int e = idx << 3;
    const int row = e >> 12;                                // /KDIM
    const int z = zp[row];
    const int4 a = *(const int4*)(w + e);
    const int4 b = *(const int4*)(w + e + 4);
    u16x8 v;
    v[0] = f2bf_exact((float)(a.x - z));
    v[1] = f2bf_exact((float)(a.y - z));
    v[2] = f2bf_exact((float)(a.z - z));
    v[3] = f2bf_exact((float)(a.w - z));
    v[4] = f2bf_exact((float)(b.x - z));
    v[5] = f2bf_exact((float)(b.y - z));
    v[6] = f2bf_exact((float)(b.z - z));
    v[7] = f2bf_exact((float)(b.w - z));
    *(u16x8*)(wb + e) = v;
}

__global__ void conv_x(const float* __restrict__ x, u16* __restrict__ xb) {
    const int idx = blockIdx.x * blockDim.x + threadIdx.x;
    const int e = idx << 3;
    const float4 a = *(const float4*)(x + e);
    const float4 b = *(const float4*)(x + e + 4);
    u16x8 v;
    v[0] = f2bf_rne(a.x);
    v[1] = f2bf_rne(a.y);
    v[2] = f2bf_rne(a.z);
    v[3] = f2bf_rne(a.w);
    v[4] = f2bf_rne(b.x);
    v[5] = f2bf_rne(b.y);
    v[6] = f2bf_rne(b.z);
    v[7] = f2bf_rne(b.w);
    *(u16x8*)(xb + e) = v;
}

// ---------- GEMM ----------

__device__ __forceinline__ void gload16(const u16* g, u16* l) {
    __builtin_amdgcn_global_load_lds(
        (const __attribute__((address_space(1))) unsigned int*)g,
        (__attribute__((address_space(3))) unsigned int*)l,
        16, 0, 0);
}

__global__ __launch_bounds__(256) void gemm_q(const u16* __restrict__ Xb,
                                              const u16* __restrict__ Wb,
                                              const float* __restrict__ scale,
                                              const float* __restrict__ bias,
                                              float* __restrict__ out) {
    __shared__ __align__(16) u16 As[BM * BK];
    __shared__ __align__(16) u16 Bs[BN * BK];

    const int t = threadIdx.x;
    const int w = t >> 6;
    const int lane = t & 63;

    // ---- block remap: bijective XCD chunking + GROUP_M grouped raster ----
    // bid -> (xcd chunk of 688) -> within chunk: m fastest within GROUP_M=8.
    // Each XCD owns one 8x86 supertile; resident blocks share A panel (8MB)
    // and reuse each B tile 8x out of its private L2.
    const int bid = blockIdx.y * NTILE_N + blockIdx.x;
    const int xcd = bid & 7;              // NWG % 8 == 0 -> bijective
    const int off = bid >> 3;             // 0..687
    const int swz = xcd * (NWG / 8) + off;
    const int gid = swz / (GROUP_M * NTILE_N);      // group 0..7
    const int rem = swz % (GROUP_M * NTILE_N);
    const int pm = gid * GROUP_M + (rem & (GROUP_M - 1));
    const int pn = rem >> 3;                         // / GROUP_M
    const int bn0 = pn * BN;
    const int bm0 = pm * BM;

    // staging: thread t loads 8 bf16 (16B). row = t/4 (0..63), col = (t%4)*8
    const int sr = t >> 2;
    const int sc = (t & 3) << 3;
    const u16* gA = Xb + (bm0 + sr) * KDIM + sc;
    const u16* gB = Wb + (bn0 + sr) * KDIM + sc;
    // wave-uniform LDS dests (global_load_lds writes base + lane*16B)
    u16* lA0 = &As[(w * 16) * BK];
    u16* lA1 = &As[(64 + w * 16) * BK];
    u16* lB0 = &Bs[(w * 16) * BK];
    u16* lB1 = &Bs[(64 + w * 16) * BK];

    // wave 2x2 grid, each wave 64x64 output
    const int wm = w >> 1, wn = w & 1;
    const int lr = lane & 15;          // frag row/col
    const int lk = (lane >> 4) << 3;   // frag k-offset
    const u16* pA = &As[(wm * 64 + lr) * BK + lk];
    const u16* pB = &Bs[(wn * 64 + lr) * BK + lk];

    f32x4 acc[4][4];
#pragma unroll
    for (int i = 0; i < 4; ++i)
#pragma unroll
        for (int j = 0; j < 4; ++j) acc[i][j] = (f32x4){0.f, 0.f, 0.f, 0.f};

    for (int k0 = 0; k0 < KDIM; k0 += BK) {
        gload16(gA + k0, lA0);
        gload16(gA + 64 * KDIM + k0, lA1);
        gload16(gB + k0, lB0);
        gload16(gB + 64 * KDIM + k0, lB1);
        __syncthreads();   // drains vmcnt before barrier

        bf16x8 af[4], bfr[4];
#pragma unroll
        for (int i = 0; i < 4; ++i) af[i] = *(const bf16x8*)(pA + i * 16 * BK);
#pragma unroll
        for (int j = 0; j < 4; ++j) bfr[j] = *(const bf16x8*)(pB + j * 16 * BK);
#pragma unroll
        for (int i = 0; i < 4; ++i)
#pragma unroll
            for (int j = 0; j < 4; ++j)
                acc[i][j] = __builtin_amdgcn_mfma_f32_16x16x32_bf16(
                    af[i], bfr[j], acc[i][j], 0, 0, 0);
        __syncthreads();
    }

    // epilogue: C/D layout col = lane&15, row = (lane>>4)*4 + reg  [m89]
    const int rr = (lane >> 4) << 2;
#pragma unroll
    for (int j = 0; j < 4; ++j) {
        const int n = bn0 + wn * 64 + j * 16 + lr;
        const float s = scale[n];
        const float bi = bias[n];
#pragma unroll
        for (int i = 0; i < 4; ++i) {
            const int m = bm0 + wm * 64 + i * 16 + rr;
#pragma unroll
            for (int r = 0; r < 4; ++r) {
                out[(m + r) * NDIM + n] = acc[i][j][r] * s + bi;
            }
        }
    }
}

// ---------- fallback (ws too small) ----------

__global__ void naive_q(const float* __restrict__ x, const int* __restrict__ wq,
                        const float* __restrict__ scale, const int* __restrict__ zp,
                        const float* __restrict__ bias, float* __restrict__ out) {
    const long long idx = (long long)blockIdx.x * 256 + threadIdx.x;
    if (idx >= (long long)MDIM * NDIM) return;
    const int m = (int)(idx / NDIM);
    const int n = (int)(idx % NDIM);
    const float* xr = x + (long long)m * KDIM;
    const int* wr = wq + (long long)n * KDIM;
    float dot = 0.f, xs = 0.f;
    for (int k = 0; k < KDIM; ++k) {
        dot += xr[k] * (float)wr[k];
        xs += xr[k];
    }
    out[idx] = scale[n] * (dot - (float)zp[n] * xs) + bias[n];
}

extern "C" void kernel_launch(void* const* d_in, const int* in_sizes, int n_in,
                              void* d_out, int out_size, void* d_ws, size_t ws_size,
                              hipStream_t stream) {
    const float* x = (const float*)d_in[0];
    const int* wq = (const int*)d_in[1];
    const float* scale = (const float*)d_in[2];
    const int* zp = (const int*)d_in[3];
    const float* bias = (const float*)d_in[4];
    float* out = (float*)d_out;

    const size_t wb_bytes = (size_t)NDIM * KDIM * 2;  // 90,177,536
    const size_t xb_bytes = (size_t)MDIM * KDIM * 2;  // 67,108,864

    if (ws_size >= wb_bytes + xb_bytes) {
        u16* wb = (u16*)d_ws;
        u16* xb = (u16*)((char*)d_ws + wb_bytes);
        conv_w<<<NDIM * KDIM / 8 / 256, 256, 0, stream>>>(wq, zp, wb);
        conv_x<<<MDIM * KDIM / 8 / 256, 256, 0, stream>>>(x, xb);
        dim3 grid(NTILE_N, NTILE_M);  // (86, 64)
        gemm_q<<<grid, 256, 0, stream>>>(xb, wb, scale, bias, out);
    } else {
        const long long total = (long long)MDIM * NDIM;
        naive_q<<<(unsigned)((total + 255) / 256), 256, 0, stream>>>(
            x, wq, scale, zp, bias, out);
    }
}

// Round 4
// 817.231 us; speedup vs baseline: 1.6422x; 1.2202x over previous
//
#include <hip/hip_runtime.h>
#include <hip/hip_bf16.h>

// CustomQuantLinear: out[m][n] = scale[n] * sum_k x[m][k]*(w[n][k]-zp[n]) + bias[n]
// M=8192, N=11008, K=4096.  W' = (w-zp) in bf16 (exact), x rounded to bf16.
// R3 -> R4: m97 structure hit its ceiling (MfmaUtil 35%). Port the deep-pipelined
// 256^2 schedule: 4-slot LDS ring, counted vmcnt(8) (never 0 in main loop),
// raw s_barrier phases, st-swizzled LDS reads, setprio around MFMA.
// Ledger: group t computes slot t%4, stages tile t+3 into slot (t-1)%4 (reads
// done at end of group t-1 -> no overwrite hazard); vmcnt(8) at group end
// forces tile t+1 landed (tiles t+2,t+3 = 8 loads stay in flight).

#define MDIM 8192
#define NDIM 11008
#define KDIM 4096

#define BM 256
#define BN 256
#define BK 32
#define KT (KDIM / BK)   // 128
#define NTM (MDIM / BM)  // 32
#define NTN (NDIM / BN)  // 43
#define NWG (NTM * NTN)  // 1376 = 8*172

typedef unsigned short u16;
typedef __bf16 bf16x8 __attribute__((ext_vector_type(8)));
typedef float f32x4 __attribute__((ext_vector_type(4)));
typedef u16 u16x8 __attribute__((ext_vector_type(8)));

// ---------- conversion kernels ----------

__device__ __forceinline__ u16 f2bf_exact(float f) {
    return (u16)(__float_as_uint(f) >> 16);
}
__device__ __forceinline__ u16 f2bf_rne(float f) {
    unsigned u = __float_as_uint(f);
    u += 0x7fffu + ((u >> 16) & 1u);
    return (u16)(u >> 16);
}

__global__ void conv_w(const int* __restrict__ w, const int* __restrict__ zp,
                       u16* __restrict__ wb) {
    const int idx = blockIdx.x * blockDim.x + threadIdx.x;
    const int e = idx << 3;
    const int row = e >> 12;
    const int z = zp[row];
    const int4 a = *(const int4*)(w + e);
    const int4 b = *(const int4*)(w + e + 4);
    u16x8 v;
    v[0] = f2bf_exact((float)(a.x - z));
    v[1] = f2bf_exact((float)(a.y - z));
    v[2] = f2bf_exact((float)(a.z - z));
    v[3] = f2bf_exact((float)(a.w - z));
    v[4] = f2bf_exact((float)(b.x - z));
    v[5] = f2bf_exact((float)(b.y - z));
    v[6] = f2bf_exact((float)(b.z - z));
    v[7] = f2bf_exact((float)(b.w - z));
    *(u16x8*)(wb + e) = v;
}

__global__ void conv_x(const float* __restrict__ x, u16* __restrict__ xb) {
    const int idx = blockIdx.x * blockDim.x + threadIdx.x;
    const int e = idx << 3;
    const float4 a = *(const float4*)(x + e);
    const float4 b = *(const float4*)(x + e + 4);
    u16x8 v;
    v[0] = f2bf_rne(a.x);
    v[1] = f2bf_rne(a.y);
    v[2] = f2bf_rne(a.z);
    v[3] = f2bf_rne(a.w);
    v[4] = f2bf_rne(b.x);
    v[5] = f2bf_rne(b.y);
    v[6] = f2bf_rne(b.z);
    v[7] = f2bf_rne(b.w);
    *(u16x8*)(xb + e) = v;
}

// ---------- GEMM ----------

__device__ __forceinline__ void gload16(const u16* g, u16* l) {
    __builtin_amdgcn_global_load_lds(
        (const __attribute__((address_space(1))) unsigned int*)g,
        (__attribute__((address_space(3))) unsigned int*)l, 16, 0, 0);
}

// stage one K-tile operand (A or B): 512 thr * 2 loads * 16B = 16KB = [256][32] bf16
#define STAGE_A(T) do { const int _s = (T) & 3; const int _k = (T) * BK;          \
    gload16(gA0 + _k, &SH[_s][0][wid * 512]);                                     \
    gload16(gA1 + _k, &SH[_s][0][4096 + wid * 512]); } while (0)
#define STAGE_B(T) do { const int _s = (T) & 3; const int _k = (T) * BK;          \
    gload16(gB0 + _k, &SH[_s][1][wid * 512]);                                     \
    gload16(gB1 + _k, &SH[_s][1][4096 + wid * 512]); } while (0)

// one K-tile group: 2 phases, 32 MFMA/wave, 12 ds_read_b128/wave
#define GROUP(T, DO_STAGE, WAITOP) do {                                           \
    const u16* _sA = &SH[(T) & 3][0][0];                                          \
    const u16* _sB = &SH[(T) & 3][1][0];                                          \
    bf16x8 aF[4], bF[4], aG[4];                                                   \
    _Pragma("unroll") for (int _f = 0; _f < 4; ++_f) {                            \
        aF[_f] = *(const bf16x8*)(_sA + aoff + _f * 512);                         \
        bF[_f] = *(const bf16x8*)(_sB + boff + _f * 512);                         \
    }                                                                             \
    if (DO_STAGE) STAGE_A((T) + 3);                                               \
    __builtin_amdgcn_s_barrier();                                                 \
    __builtin_amdgcn_s_setprio(1);                                                \
    _Pragma("unroll") for (int _i = 0; _i < 4; ++_i)                              \
    _Pragma("unroll") for (int _j = 0; _j < 4; ++_j)                              \
        acc[_i][_j] = __builtin_amdgcn_mfma_f32_16x16x32_bf16(                    \
            aF[_i], bF[_j], acc[_i][_j], 0, 0, 0);                                \
    __builtin_amdgcn_s_setprio(0);                                                \
    __builtin_amdgcn_s_barrier();                                                 \
    _Pragma("unroll") for (int _f = 0; _f < 4; ++_f)                              \
        aG[_f] = *(const bf16x8*)(_sA + aoff + (_f + 4) * 512);                   \
    if (DO_STAGE) STAGE_B((T) + 3);                                               \
    __builtin_amdgcn_s_barrier();                                                 \
    __builtin_amdgcn_s_setprio(1);                                                \
    _Pragma("unroll") for (int _i = 0; _i < 4; ++_i)                              \
    _Pragma("unroll") for (int _j = 0; _j < 4; ++_j)                              \
        acc[_i + 4][_j] = __builtin_amdgcn_mfma_f32_16x16x32_bf16(                \
            aG[_i], bF[_j], acc[_i + 4][_j], 0, 0, 0);                            \
    __builtin_amdgcn_s_setprio(0);                                                \
    WAITOP;                                                                       \
    __builtin_amdgcn_s_barrier();                                                 \
} while (0)

__global__ __launch_bounds__(512, 2) void gemm_q(const u16* __restrict__ Xb,
                                                 const u16* __restrict__ Wb,
                                                 const float* __restrict__ scale,
                                                 const float* __restrict__ bias,
                                                 float* __restrict__ out) {
    __shared__ __align__(16) u16 SH[4][2][8192];  // [slot][A|B][256*32] = 128 KiB

    const int tid = threadIdx.x;
    const int wid = tid >> 6;
    const int lane = tid & 63;

    // bijective XCD raster: xcd = bid&7 owns M-tiles 4x..4x+3, n slowest
    const int bid = blockIdx.x;
    const int pm = ((bid & 7) << 2) | ((bid >> 3) & 3);
    const int pn = bid >> 5;                        // 0..42
    const int bm0 = pm * BM;
    const int bn0 = pn * BN;

    // staging: thread tid covers row (tid>>2)+j*128, 8 cols at swizzled offset.
    // LDS dest is linear (gload_lds); source col pre-swizzled so that
    // physical[P] = logical[P ^ ((P>>9&1)<<5)]  (st-swizzle, involution).
    const int srow = tid >> 2;
    const int scol = ((tid & 3) << 3) ^ (((tid >> 5) & 1) << 4);
    const u16* gA0 = Xb + (bm0 + srow) * KDIM + scol;
    const u16* gA1 = Xb + (bm0 + srow + 128) * KDIM + scol;
    const u16* gB0 = Wb + (bn0 + srow) * KDIM + scol;
    const u16* gB1 = Wb + (bn0 + srow + 128) * KDIM + scol;

    // fragment read offsets (u16 idx, swizzle applied on read)
    const int wm = wid >> 2, wn = wid & 3;
    const int lr = lane & 15;
    const int kb = (lane >> 4) << 4;                // byte offset in row: 0,16,32,48
    const int swz = ((lr >> 3) & 1) << 5;           // row bit3 -> byte bit5
    const int aoff = ((((wm * 128 + lr) * 64) + kb) ^ swz) >> 1;
    const int boff = ((((wn * 64 + lr) * 64) + kb) ^ swz) >> 1;

    f32x4 acc[8][4];
#pragma unroll
    for (int i = 0; i < 8; ++i)
#pragma unroll
        for (int j = 0; j < 4; ++j) acc[i][j] = (f32x4){0.f, 0.f, 0.f, 0.f};

    // prologue: stage tiles 0,1,2 (12 loads); tile 0 landed after vmcnt(8)
    STAGE_A(0); STAGE_B(0);
    STAGE_A(1); STAGE_B(1);
    STAGE_A(2); STAGE_B(2);
    asm volatile("s_waitcnt vmcnt(8)" ::: "memory");
    __builtin_amdgcn_s_barrier();

    for (int t = 0; t < KT - 3; ++t) {  // 0..124, stages tiles 3..127
        GROUP(t, true, asm volatile("s_waitcnt vmcnt(8)" ::: "memory"));
    }
    GROUP(KT - 3, false, asm volatile("s_waitcnt vmcnt(4)" ::: "memory"));
    GROUP(KT - 2, false, asm volatile("s_waitcnt vmcnt(0)" ::: "memory"));
    GROUP(KT - 1, false, (void)0);

    // epilogue: C/D layout col = lane&15, row = (lane>>4)*4 + reg  [m89]
    const int rr = (lane >> 4) << 2;
#pragma unroll
    for (int j = 0; j < 4; ++j) {
        const int n = bn0 + wn * 64 + j * 16 + lr;
        const float s = scale[n];
        const float bi = bias[n];
#pragma unroll
        for (int i = 0; i < 8; ++i) {
            const int m = bm0 + wm * 128 + i * 16 + rr;
#pragma unroll
            for (int r = 0; r < 4; ++r) {
                out[(size_t)(m + r) * NDIM + n] = acc[i][j][r] * s + bi;
            }
        }
    }
}

// ---------- fallback (ws too small) ----------

__global__ void naive_q(const float* __restrict__ x, const int* __restrict__ wq,
                        const float* __restrict__ scale, const int* __restrict__ zp,
                        const float* __restrict__ bias, float* __restrict__ out) {
    const long long idx = (long long)blockIdx.x * 256 + threadIdx.x;
    if (idx >= (long long)MDIM * NDIM) return;
    const int m = (int)(idx / NDIM);
    const int n = (int)(idx % NDIM);
    const float* xr = x + (long long)m * KDIM;
    const int* wr = wq + (long long)n * KDIM;
    float dot = 0.f, xs = 0.f;
    for (int k = 0; k < KDIM; ++k) {
        dot += xr[k] * (float)wr[k];
        xs += xr[k];
    }
    out[idx] = scale[n] * (dot - (float)zp[n] * xs) + bias[n];
}

extern "C" void kernel_launch(void* const* d_in, const int* in_sizes, int n_in,
                              void* d_out, int out_size, void* d_ws, size_t ws_size,
                              hipStream_t stream) {
    const float* x = (const float*)d_in[0];
    const int* wq = (const int*)d_in[1];
    const float* scale = (const float*)d_in[2];
    const int* zp = (const int*)d_in[3];
    const float* bias = (const float*)d_in[4];
    float* out = (float*)d_out;

    const size_t wb_bytes = (size_t)NDIM * KDIM * 2;  // 90,177,536
    const size_t xb_bytes = (size_t)MDIM * KDIM * 2;  // 67,108,864

    if (ws_size >= wb_bytes + xb_bytes) {
        u16* wb = (u16*)d_ws;
        u16* xb = (u16*)((char*)d_ws + wb_bytes);
        conv_w<<<NDIM * KDIM / 8 / 256, 256, 0, stream>>>(wq, zp, wb);
        conv_x<<<MDIM * KDIM / 8 / 256, 256, 0, stream>>>(x, xb);
        gemm_q<<<NWG, 512, 0, stream>>>(xb, wb, scale, bias, out);
    } else {
        const long long total = (long long)MDIM * NDIM;
        naive_q<<<(unsigned)((total + 255) / 256), 256, 0, stream>>>(
            x, wq, scale, zp, bias, out);
    }
}

// Round 5
// 565.753 us; speedup vs baseline: 2.3721x; 1.4445x over previous
//
#include <hip/hip_runtime.h>
#include <hip/hip_bf16.h>

// CustomQuantLinear: out[m][n] = scale[n] * sum_k x[m][k]*(w[n][k]-zp[n]) + bias[n]
// M=8192, N=11008, K=4096.
// R4 -> R5: int8 MFMA path. w fits int8 exactly; quantize x per-row to int8
// (sx[m] = absmax/127) and keep the zp term exact via fp32 rowsum of original x:
//   out = scale[n] * (sx[m]*dotq[m][n] - zp[n]*xsum[m]) + bias[n],
//   dotq = sum_k xq[m][k]*w[n][k]  via mfma_i32_16x16x64_i8 (2x bf16 rate).
// GEMM keeps R4's verified structure byte-for-byte: [256][64B] LDS rows,
// XOR-bit5 swizzle (0 bank conflicts), 4-slot ring, counted vmcnt(8),
// raw s_barrier phases, setprio around MFMA. KT halves (64 groups of K=64).

#define MDIM 8192
#define NDIM 11008
#define KDIM 4096

#define BM 256
#define BN 256
#define BK 64
#define KT (KDIM / BK)   // 64
#define NTM (MDIM / BM)  // 32
#define NTN (NDIM / BN)  // 43
#define NWG (NTM * NTN)  // 1376 = 8*172

typedef signed char i8;
typedef int i32x4 __attribute__((ext_vector_type(4)));

// ---------- prep kernels ----------

// pack w (int32 in [-128,127]) -> int8, 16 elems/thread
__global__ void conv_w8(const int* __restrict__ w, i8* __restrict__ w8) {
    const size_t e = ((size_t)blockIdx.x * 256 + threadIdx.x) << 4;
    const int4 a = *(const int4*)(w + e);
    const int4 b = *(const int4*)(w + e + 4);
    const int4 c = *(const int4*)(w + e + 8);
    const int4 d = *(const int4*)(w + e + 12);
    i8 q[16];
    q[0] = (i8)a.x; q[1] = (i8)a.y; q[2] = (i8)a.z; q[3] = (i8)a.w;
    q[4] = (i8)b.x; q[5] = (i8)b.y; q[6] = (i8)b.z; q[7] = (i8)b.w;
    q[8] = (i8)c.x; q[9] = (i8)c.y; q[10] = (i8)c.z; q[11] = (i8)c.w;
    q[12] = (i8)d.x; q[13] = (i8)d.y; q[14] = (i8)d.z; q[15] = (i8)d.w;
    *(int4*)(w8 + e) = *(const int4*)q;
}

// per-row x quant: xq = rint(x*127/absmax), sx = absmax/127, xs = sum(x) fp32
__global__ __launch_bounds__(256) void conv_xq(const float* __restrict__ x,
                                               i8* __restrict__ xq,
                                               float* __restrict__ sx,
                                               float* __restrict__ xs) {
    __shared__ float ramax[4], rsum[4];
    const int row = blockIdx.x;
    const float* xr = x + (size_t)row * KDIM;
    const int t = threadIdx.x;
    const float4* p = (const float4*)xr + (t << 2);
    float4 v0 = p[0], v1 = p[1], v2 = p[2], v3 = p[3];
    float amax = 0.f, sum = 0.f;
    float vv[16] = {v0.x, v0.y, v0.z, v0.w, v1.x, v1.y, v1.z, v1.w,
                    v2.x, v2.y, v2.z, v2.w, v3.x, v3.y, v3.z, v3.w};
#pragma unroll
    for (int i = 0; i < 16; ++i) {
        amax = fmaxf(amax, fabsf(vv[i]));
        sum += vv[i];
    }
#pragma unroll
    for (int off = 32; off > 0; off >>= 1) {
        amax = fmaxf(amax, __shfl_down(amax, off, 64));
        sum += __shfl_down(sum, off, 64);
    }
    if ((t & 63) == 0) { ramax[t >> 6] = amax; rsum[t >> 6] = sum; }
    __syncthreads();
    amax = fmaxf(fmaxf(ramax[0], ramax[1]), fmaxf(ramax[2], ramax[3]));
    sum = (rsum[0] + rsum[1]) + (rsum[2] + rsum[3]);
    const float inv = (amax > 0.f) ? 127.0f / amax : 0.f;
    if (t == 0) {
        sx[row] = amax * (1.0f / 127.0f);
        xs[row] = sum;
    }
    i8 q[16];
#pragma unroll
    for (int i = 0; i < 16; ++i) q[i] = (i8)(int)rintf(vv[i] * inv);
    *(int4*)(xq + (size_t)row * KDIM + (t << 4)) = *(const int4*)q;
}

// ---------- GEMM ----------

__device__ __forceinline__ void gload16(const i8* g, i8* l) {
    __builtin_amdgcn_global_load_lds(
        (const __attribute__((address_space(1))) unsigned int*)g,
        (__attribute__((address_space(3))) unsigned int*)l, 16, 0, 0);
}

// stage one K-tile operand: [256 rows][64 cols] i8 = 16KB = 512 thr * 2 * 16B
#define STAGE_A(T) do { const int _s = (T) & 3; const int _k = (T) * BK;          \
    gload16(gA0 + _k, &SH[_s][0][wid * 1024]);                                    \
    gload16(gA1 + _k, &SH[_s][0][8192 + wid * 1024]); } while (0)
#define STAGE_B(T) do { const int _s = (T) & 3; const int _k = (T) * BK;          \
    gload16(gB0 + _k, &SH[_s][1][wid * 1024]);                                    \
    gload16(gB1 + _k, &SH[_s][1][8192 + wid * 1024]); } while (0)

// one K-tile group: 2 phases, 32 MFMA/wave (16x16x64 i8), 12 ds_read_b128/wave
#define GROUP(T, DO_STAGE, WAITOP) do {                                           \
    const i8* _sA = &SH[(T) & 3][0][0];                                           \
    const i8* _sB = &SH[(T) & 3][1][0];                                           \
    i32x4 aF[4], bF[4], aG[4];                                                    \
    _Pragma("unroll") for (int _f = 0; _f < 4; ++_f) {                            \
        aF[_f] = *(const i32x4*)(_sA + aoff + _f * 1024);                         \
        bF[_f] = *(const i32x4*)(_sB + boff + _f * 1024);                         \
    }                                                                             \
    if (DO_STAGE) STAGE_A((T) + 3);                                               \
    __builtin_amdgcn_s_barrier();                                                 \
    __builtin_amdgcn_s_setprio(1);                                                \
    _Pragma("unroll") for (int _i = 0; _i < 4; ++_i)                              \
    _Pragma("unroll") for (int _j = 0; _j < 4; ++_j)                              \
        acc[_i][_j] = __builtin_amdgcn_mfma_i32_16x16x64_i8(                      \
            aF[_i], bF[_j], acc[_i][_j], 0, 0, 0);                                \
    __builtin_amdgcn_s_setprio(0);                                                \
    __builtin_amdgcn_s_barrier();                                                 \
    _Pragma("unroll") for (int _f = 0; _f < 4; ++_f)                              \
        aG[_f] = *(const i32x4*)(_sA + aoff + (_f + 4) * 1024);                   \
    if (DO_STAGE) STAGE_B((T) + 3);                                               \
    __builtin_amdgcn_s_barrier();                                                 \
    __builtin_amdgcn_s_setprio(1);                                                \
    _Pragma("unroll") for (int _i = 0; _i < 4; ++_i)                              \
    _Pragma("unroll") for (int _j = 0; _j < 4; ++_j)                              \
        acc[_i + 4][_j] = __builtin_amdgcn_mfma_i32_16x16x64_i8(                  \
            aG[_i], bF[_j], acc[_i + 4][_j], 0, 0, 0);                            \
    __builtin_amdgcn_s_setprio(0);                                                \
    WAITOP;                                                                       \
    __builtin_amdgcn_s_barrier();                                                 \
} while (0)

__global__ __launch_bounds__(512, 2) void gemm_q(const i8* __restrict__ Xq,
                                                 const i8* __restrict__ Wq,
                                                 const float* __restrict__ sx,
                                                 const float* __restrict__ xs,
                                                 const float* __restrict__ scale,
                                                 const int* __restrict__ zp,
                                                 const float* __restrict__ bias,
                                                 float* __restrict__ out) {
    __shared__ __align__(16) i8 SH[4][2][16384];  // [slot][A|B][256*64] = 128 KiB

    const int tid = threadIdx.x;
    const int wid = tid >> 6;
    const int lane = tid & 63;

    // bijective XCD raster: xcd = bid&7 owns M-tiles 4x..4x+3, n slowest
    const int bid = blockIdx.x;
    const int pm = ((bid & 7) << 2) | ((bid >> 3) & 3);
    const int pn = bid >> 5;
    const int bm0 = pm * BM;
    const int bn0 = pn * BN;

    // staging: thread covers row (tid>>2)(+128), 16 cols at swizzled source col.
    // LDS dest linear (gload_lds); physical[P] = logical[P ^ ((row&8)<<2)].
    const int srow = tid >> 2;
    const int scol = ((tid & 3) << 4) ^ (((tid >> 5) & 1) << 5);
    const i8* gA0 = Xq + (size_t)(bm0 + srow) * KDIM + scol;
    const i8* gA1 = gA0 + (size_t)128 * KDIM;
    const i8* gB0 = Wq + (size_t)(bn0 + srow) * KDIM + scol;
    const i8* gB1 = gB0 + (size_t)128 * KDIM;

    // fragment read offsets (bytes, swizzle applied on read)
    const int wm = wid >> 2, wn = wid & 3;
    const int lr = lane & 15;
    const int kb = (lane >> 4) << 4;            // 0,16,32,48 byte col
    const int swz = (lr & 8) << 2;              // row bit3 -> byte bit5
    const int aoff = (((wm * 128 + lr) << 6) + kb) ^ swz;
    const int boff = (((wn * 64 + lr) << 6) + kb) ^ swz;

    i32x4 acc[8][4];
#pragma unroll
    for (int i = 0; i < 8; ++i)
#pragma unroll
        for (int j = 0; j < 4; ++j) acc[i][j] = (i32x4){0, 0, 0, 0};

    // prologue: stage tiles 0,1,2 (12 loads/wave); tile 0 landed after vmcnt(8)
    STAGE_A(0); STAGE_B(0);
    STAGE_A(1); STAGE_B(1);
    STAGE_A(2); STAGE_B(2);
    asm volatile("s_waitcnt vmcnt(8)" ::: "memory");
    __builtin_amdgcn_s_barrier();

    for (int t = 0; t < KT - 3; ++t) {  // stages tiles 3..63
        GROUP(t, true, asm volatile("s_waitcnt vmcnt(8)" ::: "memory"));
    }
    GROUP(KT - 3, false, asm volatile("s_waitcnt vmcnt(4)" ::: "memory"));
    GROUP(KT - 2, false, asm volatile("s_waitcnt vmcnt(0)" ::: "memory"));
    GROUP(KT - 1, false, (void)0);

    // epilogue: C/D layout col = lane&15, row = (lane>>4)*4 + reg (shape-determined)
    const int rr = (lane >> 4) << 2;
#pragma unroll
    for (int j = 0; j < 4; ++j) {
        const int n = bn0 + wn * 64 + j * 16 + lr;
        const float sc = scale[n];
        const float zpn = (float)zp[n];
        const float bi = bias[n];
#pragma unroll
        for (int i = 0; i < 8; ++i) {
            const int m = bm0 + wm * 128 + i * 16 + rr;
#pragma unroll
            for (int r = 0; r < 4; ++r) {
                const int mm = m + r;
                const float d = (float)acc[i][j][r];
                out[(size_t)mm * NDIM + n] = sc * (sx[mm] * d - zpn * xs[mm]) + bi;
            }
        }
    }
}

// ---------- fallback (ws too small) ----------

__global__ void naive_q(const float* __restrict__ x, const int* __restrict__ wq,
                        const float* __restrict__ scale, const int* __restrict__ zp,
                        const float* __restrict__ bias, float* __restrict__ out) {
    const long long idx = (long long)blockIdx.x * 256 + threadIdx.x;
    if (idx >= (long long)MDIM * NDIM) return;
    const int m = (int)(idx / NDIM);
    const int n = (int)(idx % NDIM);
    const float* xr = x + (long long)m * KDIM;
    const int* wr = wq + (long long)n * KDIM;
    float dot = 0.f, xsum = 0.f;
    for (int k = 0; k < KDIM; ++k) {
        dot += xr[k] * (float)wr[k];
        xsum += xr[k];
    }
    out[idx] = scale[n] * (dot - (float)zp[n] * xsum) + bias[n];
}

extern "C" void kernel_launch(void* const* d_in, const int* in_sizes, int n_in,
                              void* d_out, int out_size, void* d_ws, size_t ws_size,
                              hipStream_t stream) {
    const float* x = (const float*)d_in[0];
    const int* wq = (const int*)d_in[1];
    const float* scale = (const float*)d_in[2];
    const int* zp = (const int*)d_in[3];
    const float* bias = (const float*)d_in[4];
    float* out = (float*)d_out;

    const size_t w8_bytes = (size_t)NDIM * KDIM;      // 45,088,768
    const size_t xq_bytes = (size_t)MDIM * KDIM;      // 33,554,432
    const size_t row_bytes = (size_t)MDIM * 4;        // 32,768
    const size_t need = w8_bytes + xq_bytes + 2 * row_bytes;

    if (ws_size >= need) {
        i8* w8 = (i8*)d_ws;
        i8* xq8 = (i8*)((char*)d_ws + w8_bytes);
        float* sx = (float*)((char*)d_ws + w8_bytes + xq_bytes);
        float* xs = (float*)((char*)d_ws + w8_bytes + xq_bytes + row_bytes);
        conv_w8<<<(unsigned)(w8_bytes / 16 / 256), 256, 0, stream>>>(wq, w8);
        conv_xq<<<MDIM, 256, 0, stream>>>(x, xq8, sx, xs);
        gemm_q<<<NWG, 512, 0, stream>>>(xq8, w8, sx, xs, scale, zp, bias, out);
    } else {
        const long long total = (long long)MDIM * NDIM;
        naive_q<<<(unsigned)((total + 255) / 256), 256, 0, stream>>>(
            x, wq, scale, zp, bias, out);
    }
}